// Round 20
// baseline (132.576 us; speedup 1.0000x reference)
//
#include <hip/hip_runtime.h>

#define L_SEQ 1024
#define NB 8
#define NM 64
#define LM (L_SEQ * NM)    // 65536
#define BLM (NB * LM)      // 524288
#define RS8 0.35355339059327373f
#define LOG2E 1.4426950408889634f

typedef unsigned short u16;
typedef unsigned int u32;
typedef __attribute__((ext_vector_type(8))) short short8;
typedef __attribute__((ext_vector_type(4))) float f32x4;
typedef __attribute__((ext_vector_type(8))) u16 us8;

__device__ __forceinline__ float wredsum(float v) {
#pragma unroll
    for (int off = 32; off; off >>= 1) v += __shfl_xor(v, off);
    return v;
}

__device__ __forceinline__ u16 f2bf(float f) {
    u32 u = __float_as_uint(f);
    u32 r = (u + 0x7FFFu + ((u >> 16) & 1u)) >> 16;
    return (u16)r;
}
__device__ __forceinline__ float bf2f(u16 u) {
    return __uint_as_float((u32)u << 16);
}
// packed RNE f32->bf16 pair (1 VALU op)
__device__ __forceinline__ u32 cvtpk(float lo, float hi) {
    u32 r;
    asm("v_cvt_pk_bf16_f32 %0, %1, %2" : "=v"(r) : "v"(lo), "v"(hi));
    return r;
}

// direct global->LDS DMA, 16 B per lane; dest = lds_base + lane*16 (wave-uniform base)
__device__ __forceinline__ void gll16(const u16* g, u16* l) {
    __builtin_amdgcn_global_load_lds(
        (const __attribute__((address_space(1))) void*)g,
        (__attribute__((address_space(3))) void*)l,
        16, 0, 0);
}

// ---------------- Prep: W fp32 -> bf16; x -> xT bf16; also zeroes the phase barrier counter ------
__global__ __launch_bounds__(256) void prep_kernel(
        const float* __restrict__ x, const float* __restrict__ Wq,
        const float* __restrict__ Wk, const float* __restrict__ Wv,
        u16* __restrict__ Wbf, u16* __restrict__ xT, int* __restrict__ cnt) {
    const int bx = blockIdx.x;
    const int tid = threadIdx.x;
    if (bx == 0 && tid == 0) *cnt = 0;     // barrier counter for the fused kernel (next node)
    if (bx < 1536) {                       // W convert: 3 x 512 blocks x 2048 elements
        const int w = bx >> 9;
        const int blk = bx & 511;
        const float* W = (w == 0) ? Wq : (w == 1) ? Wk : Wv;
        const size_t base = (size_t)blk * 2048 + (size_t)tid * 8;
        float4 f0 = *(const float4*)&W[base];
        float4 f1 = *(const float4*)&W[base + 4];
        us8 o;
        o[0] = f2bf(f0.x); o[1] = f2bf(f0.y); o[2] = f2bf(f0.z); o[3] = f2bf(f0.w);
        o[4] = f2bf(f1.x); o[5] = f2bf(f1.y); o[6] = f2bf(f1.z); o[7] = f2bf(f1.w);
        *(us8*)&Wbf[(size_t)w * 1048576 + base] = o;
    } else {                               // x transpose: 128 blocks (b, ktile)
        const int blk = bx - 1536;
        const int b = blk >> 4, kt = blk & 15;
        __shared__ float T[64][65];
        const int r16 = tid >> 4, c4 = (tid & 15) * 4;
#pragma unroll
        for (int s = 0; s < 4; s++) {
            int r = r16 + s * 16;
            *(float4*)&T[r][c4] = *(const float4*)&x[((size_t)b * L_SEQ + kt * 64 + r) * NM + c4];
        }
        __syncthreads();
        const int m = tid >> 2;
#pragma unroll
        for (int s = 0; s < 2; s++) {
            int c = (tid & 3) * 2 + s;
            int k0 = c * 8;
            us8 o;
#pragma unroll
            for (int j = 0; j < 8; j++) o[j] = f2bf(T[k0 + j][m]);
            *(us8*)&xT[((size_t)b * NM + m) * L_SEQ + kt * 64 + k0] = o;
        }
    }
}

// ============ Fused proj + attn(+out2): 768 blocks, in-kernel device-scope barrier ============
// Phase A (all 768 blocks): proj unit u = b + 8*it + 256*w (round-19 body, GLL staging).
// Barrier: syncthreads (drains vmem) -> release fetch_add -> blocks >=520 exit ->
//          spinners acquire-load until 768 -> syncthreads.
// Phase B: u<512 = attn pair unit (s,c,b); u in [512,520) = out2 batch. Round-19 bodies.
// Co-residency: LDS 48KB -> 3 blocks/CU (768); VGPR capped <=128 by launch_bounds(256,4).
// Deadlock-free: spinners = 520 <= 768 capacity; non-spinners arrive then exit.
__global__ __launch_bounds__(256, 4) void projattn(
        const u16* __restrict__ Wbf, const u16* __restrict__ xT,
        u16* __restrict__ H, u16* __restrict__ VtG,
        const float* __restrict__ x, const float* __restrict__ pm,
        float* __restrict__ out, int* __restrict__ cnt) {
    __shared__ __align__(16) u16 smem[24576];   // 48 KB union

    const int u = blockIdx.x;    // 0..767
    const int tid = threadIdx.x;
    const int wv = tid >> 6, l = tid & 63;
    const int frow = l & 15;
    const int fg = l >> 4;
    const int lx = l & 7;

    // ---------------- Phase A: projection (round-19 proj_mfma body) ----------------
    {
        const int b  = u & 7;
        const int it = (u >> 3) & 31;
        const int w  = u >> 8;

        u16* Abw = &smem[wv * 2048];            // per-wave [32 rows][64 k] swizzled
        u16* Bbw = &smem[8192 + wv * 4096];     // per-wave [64 m][64 k] swizzled

        const u16* As = Wbf + (size_t)w * 1048576 + (size_t)(it * 32) * L_SEQ;
        const u16* Bs = xT + (size_t)b * (NM * L_SEQ);

        const int soff = (l >> 3) * L_SEQ + (((l & 7) ^ (l >> 3)) * 8);

        f32x4 acc[2][4];
#pragma unroll
        for (int i = 0; i < 2; i++)
#pragma unroll
            for (int j = 0; j < 4; j++) acc[i][j] = (f32x4){0.f, 0.f, 0.f, 0.f};

#define ISSUE(kt) do { \
    _Pragma("unroll") for (int ti = 0; ti < 4; ti++) \
        gll16(&As[(size_t)ti * 8192 + soff + (kt) * 64], &Abw[ti * 512]); \
    _Pragma("unroll") for (int ti = 0; ti < 8; ti++) \
        gll16(&Bs[(size_t)ti * 8192 + soff + (kt) * 64], &Bbw[ti * 512]); \
} while (0)

        const int kt0 = wv * 4;
        ISSUE(kt0);
        asm volatile("s_waitcnt vmcnt(0)" ::: "memory");
        __builtin_amdgcn_sched_barrier(0);

        for (int ii = 0; ii < 4; ++ii) {
            short8 af[2][2], bf[2][4];
#pragma unroll
            for (int ks = 0; ks < 2; ++ks) {
                const int ch = ((ks * 4 + fg) ^ lx) * 8;
                af[ks][0] = *(const short8*)&Abw[frow * 64 + ch];
                af[ks][1] = *(const short8*)&Abw[(16 + frow) * 64 + ch];
#pragma unroll
                for (int cg = 0; cg < 4; ++cg)
                    bf[ks][cg] = *(const short8*)&Bbw[(cg * 16 + frow) * 64 + ch];
            }
            asm volatile("s_waitcnt lgkmcnt(0)" ::: "memory");   // frags in VGPRs before DMA overwrite
            __builtin_amdgcn_sched_barrier(0);
            if (ii < 3) ISSUE(kt0 + ii + 1);                     // DMAs fly during MFMAs
#pragma unroll
            for (int ks = 0; ks < 2; ++ks)
#pragma unroll
                for (int cg = 0; cg < 4; ++cg) {
                    acc[0][cg] = __builtin_amdgcn_mfma_f32_16x16x32_bf16(af[ks][0], bf[ks][cg], acc[0][cg], 0, 0, 0);
                    acc[1][cg] = __builtin_amdgcn_mfma_f32_16x16x32_bf16(af[ks][1], bf[ks][cg], acc[1][cg], 0, 0, 0);
                }
            if (ii < 3) {
                asm volatile("s_waitcnt vmcnt(0)" ::: "memory"); // next tile landed before its ds_reads
                __builtin_amdgcn_sched_barrier(0);
            }
        }
#undef ISSUE

        // ---- reduce 4 K-partials through the Bb region (fp32 view), then parallel epilogue ----
        __syncthreads();
        float* Pp = (float*)&smem[8192];       // 8192 floats; partial wv at [wv*2048, +2048)
#pragma unroll
        for (int rg = 0; rg < 2; ++rg)
#pragma unroll
            for (int cg = 0; cg < 4; ++cg)
#pragma unroll
                for (int r = 0; r < 4; ++r)
                    Pp[wv * 2048 + (rg * 16 + fg * 4 + r) * 64 + cg * 16 + frow] = acc[rg][cg][r];
        __syncthreads();

        {
            const int row = wv * 8 + (l >> 3);          // 32 rows over 4 waves
            const int c8  = (l & 7) * 8;                // col group of 8
            f32x4 s0 = *(const f32x4*)&Pp[row * 64 + c8];
            f32x4 s1 = *(const f32x4*)&Pp[row * 64 + c8 + 4];
#pragma unroll
            for (int p = 1; p < 4; ++p) {
                f32x4 t0 = *(const f32x4*)&Pp[p * 2048 + row * 64 + c8];
                f32x4 t1 = *(const f32x4*)&Pp[p * 2048 + row * 64 + c8 + 4];
                s0 += t0; s1 += t1;
            }
            const int iq = it * 32 + row;
            const int c  = c8 >> 3;
            us8 o;
            o[0] = f2bf(s0[0]); o[1] = f2bf(s0[1]); o[2] = f2bf(s0[2]); o[3] = f2bf(s0[3]);
            o[4] = f2bf(s1[0]); o[5] = f2bf(s1[1]); o[6] = f2bf(s1[2]); o[7] = f2bf(s1[3]);
            u16* dst = H + (size_t)w * 524288 + (size_t)b * 65536;
            *(us8*)&dst[((size_t)c * L_SEQ + iq) * 8] = o;
            if (w == 2) {
#pragma unroll
                for (int j = 0; j < 8; ++j)
                    VtG[((size_t)(b * 8 + c) * 8 + j) * L_SEQ + iq] = o[j];
            }
        }
    }

    // ---------------- Barrier: arrive (release), gate, spin (acquire) ----------------
    __syncthreads();                           // drains all waves' vmem (H/VtG writes complete)
    if (tid == 0)
        __hip_atomic_fetch_add(cnt, 1, __ATOMIC_RELEASE, __HIP_MEMORY_SCOPE_AGENT);
    if (u >= 520) return;                      // no phase-B work: arrive-and-exit frees the slot
    if (tid == 0) {
        while (__hip_atomic_load(cnt, __ATOMIC_ACQUIRE, __HIP_MEMORY_SCOPE_AGENT) < 768)
            __builtin_amdgcn_s_sleep(8);
    }
    __syncthreads();

    // ---------------- Phase B: attention (u<512) / out2 (512<=u<520) ----------------
    u16* Kl  = smem;                           // [1024 keys][8 d] bf16 (16 KB)
    u16* Vtl = &smem[8192];                    // [8 d][1032] bf16 (16.5 KB)
    const int lane = l;

    if (u < 512) {
        const int s = u & 7, c = (u >> 3) & 7, b = u >> 6;
        const int qtil = lane & 15, g = lane >> 4;

        const size_t hoff = (size_t)(b * 8 + c) * 8192;
        const u16* HQ = H + hoff;
        const u16* HK = H + 524288 + hoff;
        const int qlo = s, qhi = 15 - s;
        const int kend = (qhi + 1) * 64;       // superset: covers both tiles' needs

        for (int k = tid; k < kend; k += 256)
            *(us8*)&Kl[k * 8] = *(const us8*)&HK[(size_t)k * 8];
        {
            const int vd = tid >> 5;
            const u16* src = VtG + ((size_t)(b * 8 + c) * 8 + vd) * L_SEQ;
            for (int k8 = (tid & 31) * 8; k8 < kend; k8 += 256)
                *(us8*)&Vtl[vd * 1032 + k8] = *(const us8*)&src[k8];
        }

        short8 qfLo = {0, 0, 0, 0, 0, 0, 0, 0};
        short8 qfHi = {0, 0, 0, 0, 0, 0, 0, 0};
        {
            const float sc = RS8 * LOG2E;
            us8 qvLo = *(const us8*)&HQ[(size_t)(qlo * 64 + wv * 16 + qtil) * 8];
            us8 qvHi = *(const us8*)&HQ[(size_t)(qhi * 64 + wv * 16 + qtil) * 8];
            if (g == 0) {
#pragma unroll
                for (int j = 0; j < 8; j++) {
                    qfLo[j] = (short)f2bf(bf2f(qvLo[j]) * sc);
                    qfHi[j] = (short)f2bf(bf2f(qvHi[j]) * sc);
                }
            }
        }

        __syncthreads();

        const f32x4 czero = {0.f, 0.f, 0.f, 0.f};
        const short8 z8 = {0, 0, 0, 0, 0, 0, 0, 0};

#define ACHUNK2(QF, ch, PRED) do { \
    const int kb_ = (ch) * 32; \
    short8 kfA_ = z8, kfB_ = z8; \
    if (g == 0) { \
        kfA_ = *(const short8*)&Kl[(kb_ + qtil) * 8]; \
        kfB_ = *(const short8*)&Kl[(kb_ + 16 + qtil) * 8]; \
    } \
    f32x4 dA_ = __builtin_amdgcn_mfma_f32_16x16x32_bf16(kfA_, QF, czero, 0, 0, 0); \
    f32x4 dB_ = __builtin_amdgcn_mfma_f32_16x16x32_bf16(kfB_, QF, czero, 0, 0, 0); \
    float pA_[4], pB_[4]; \
    const int keyA_ = kb_ + 4 * g; \
    _Pragma("unroll") for (int r_ = 0; r_ < 4; r_++) { \
        pA_[r_] = exp2f(dA_[r_]); \
        pB_[r_] = exp2f(dB_[r_]); \
        if (PRED) { \
            pA_[r_] = (keyA_ + r_ <= q_) ? pA_[r_] : 0.f; \
            pB_[r_] = (keyA_ + 16 + r_ <= q_) ? pB_[r_] : 0.f; \
        } \
        lsum_ += pA_[r_] + pB_[r_]; \
    } \
    const u32 A01_ = cvtpk(pA_[0], pA_[1]), A23_ = cvtpk(pA_[2], pA_[3]); \
    const u32 B01_ = cvtpk(pB_[0], pB_[1]), B23_ = cvtpk(pB_[2], pB_[3]); \
    const int src_ = qtil + ((g & 1) << 5); \
    const u32 a0_ = (u32)__shfl((int)A01_, src_, 64); \
    const u32 a1_ = (u32)__shfl((int)A23_, src_, 64); \
    const u32 a2_ = (u32)__shfl((int)A01_, src_ + 16, 64); \
    const u32 a3_ = (u32)__shfl((int)A23_, src_ + 16, 64); \
    const u32 b0_ = (u32)__shfl((int)B01_, src_, 64); \
    const u32 b1_ = (u32)__shfl((int)B23_, src_, 64); \
    const u32 b2_ = (u32)__shfl((int)B01_, src_ + 16, 64); \
    const u32 b3_ = (u32)__shfl((int)B23_, src_ + 16, 64); \
    union { u32 u[4]; short8 s; } pu_; \
    pu_.u[0] = (g < 2) ? a0_ : b0_; \
    pu_.u[1] = (g < 2) ? a1_ : b1_; \
    pu_.u[2] = (g < 2) ? a2_ : b2_; \
    pu_.u[3] = (g < 2) ? a3_ : b3_; \
    short8 vf_ = z8; \
    if (qtil < 8) vf_ = *(const short8*)&Vtl[qtil * 1032 + kb_ + 8 * g]; \
    oacc_ = __builtin_amdgcn_mfma_f32_16x16x32_bf16(vf_, pu_.s, oacc_, 0, 0, 0); \
} while (0)

#define RUNPASS(QF, TILE) do { \
    const int base_ = (TILE) * 64 + wv * 16; \
    const int q_ = base_ + qtil; \
    f32x4 oacc_ = czero; \
    float lsum_ = 0.f; \
    const int nfull_ = (base_ + 1) >> 5; \
    const int nch_ = (base_ + 47) >> 5; \
    for (int ch_ = 0; ch_ < nfull_; ++ch_) ACHUNK2(QF, ch_, false); \
    for (int ch_ = nfull_; ch_ < nch_; ++ch_) ACHUNK2(QF, ch_, true); \
    lsum_ += __shfl_xor(lsum_, 16); \
    lsum_ += __shfl_xor(lsum_, 32); \
    if (g < 2) { \
        const float qm_ = pm[b * L_SEQ + q_]; \
        const float r8_ = qm_ / lsum_; \
        const size_t off_ = (size_t)b * LM + (size_t)q_ * NM + c * 8 + g * 4; \
        float4 xv_ = *(const float4*)&x[off_]; \
        float4 o_ = make_float4(fmaf(oacc_[0], r8_, xv_.x), fmaf(oacc_[1], r8_, xv_.y), \
                                fmaf(oacc_[2], r8_, xv_.z), fmaf(oacc_[3], r8_, xv_.w)); \
        *(float4*)&out[off_] = o_; \
    } \
} while (0)

        RUNPASS(qfLo, qlo);
        RUNPASS(qfHi, qhi);
#undef RUNPASS
#undef ACHUNK2
    } else {
        // ---------------- out2: attention[b][k] = qm(b,1023)/8 * sum_c softmax_row_c[k] ----------
        const int b = u - 512;
        float* red = (float*)Kl;
        const float qm = pm[b * L_SEQ + 1023];
        const float sc = RS8 * LOG2E;
        float acc[4] = {0.f, 0.f, 0.f, 0.f};
        float* out2 = out + BLM;
        for (int cc = 0; cc < 8; cc++) {
            const size_t hoff = (size_t)(b * 8 + cc) * 8192;
            us8 qv = *(const us8*)&H[hoff + (size_t)1023 * 8];
            const float q0 = bf2f(qv[0]) * sc, q1 = bf2f(qv[1]) * sc;
            const float q2 = bf2f(qv[2]) * sc, q3 = bf2f(qv[3]) * sc;
            const float q4 = bf2f(qv[4]) * sc, q5 = bf2f(qv[5]) * sc;
            const float q6 = bf2f(qv[6]) * sc, q7 = bf2f(qv[7]) * sc;
            const u16* Kg = H + 524288 + hoff;
            float p[4];
            float ts = 0.f;
#pragma unroll
            for (int i = 0; i < 4; i++) {
                int k = tid + 256 * i;
                us8 kv = *(const us8*)&Kg[(size_t)k * 8];
                float sa = fmaf(q0, bf2f(kv[0]), fmaf(q1, bf2f(kv[1]), fmaf(q2, bf2f(kv[2]), q3 * bf2f(kv[3]))));
                float sb = fmaf(q4, bf2f(kv[4]), fmaf(q5, bf2f(kv[5]), fmaf(q6, bf2f(kv[6]), q7 * bf2f(kv[7]))));
                p[i] = exp2f(sa + sb);
                ts += p[i];
            }
            ts = wredsum(ts);
            if (lane == 0) red[wv] = ts;
            __syncthreads();
            const float inv = 0.125f / (red[0] + red[1] + red[2] + red[3]);
            __syncthreads();
#pragma unroll
            for (int i = 0; i < 4; i++) acc[i] = fmaf(p[i], inv, acc[i]);
        }
#pragma unroll
        for (int i = 0; i < 4; i++) out2[b * L_SEQ + tid + 256 * i] = acc[i] * qm;
    }
}

extern "C" void kernel_launch(void* const* d_in, const int* in_sizes, int n_in,
                              void* d_out, int out_size, void* d_ws, size_t ws_size,
                              hipStream_t stream) {
    const float* x  = (const float*)d_in[0];
    const float* pm = (const float*)d_in[1];
    const float* Wq = (const float*)d_in[2];
    const float* Wk = (const float*)d_in[3];
    const float* Wv = (const float*)d_in[4];

    u16* H    = (u16*)d_ws;                              // 3 MB bf16 head-major Q,K,V
    u16* Wbf  = (u16*)((char*)d_ws + 3145728);           // 6 MB bf16 W[3][1024][1024]
    u16* xT   = (u16*)((char*)d_ws + 9437184);           // 1 MB bf16 xT[8][64][1024]
    u16* VtG  = (u16*)((char*)d_ws + 10485760);          // 1 MB bf16 Vt[64 heads][8][1024]
    int* cnt  = (int*)((char*)d_ws + 12582912);          // barrier counter (zeroed by prep)
    float* out = (float*)d_out;                          // [8,1024,64] then [8,1024]

    hipLaunchKernelGGL(prep_kernel, dim3(1664), dim3(256), 0, stream, x, Wq, Wk, Wv, Wbf, xT, cnt);
    hipLaunchKernelGGL(projattn, dim3(768), dim3(256), 0, stream, Wbf, xT, H, VtG, x, pm, out, cnt);
}

// Round 21
// 42.750 us; speedup vs baseline: 3.1012x; 3.1012x over previous
//
#include <hip/hip_runtime.h>

#define L_SEQ 1024
#define NB 8
#define NM 64
#define LM (L_SEQ * NM)    // 65536
#define BLM (NB * LM)      // 524288
#define RS8 0.35355339059327373f
#define LOG2E 1.4426950408889634f

typedef unsigned short u16;
typedef unsigned int u32;
typedef __attribute__((ext_vector_type(8))) short short8;
typedef __attribute__((ext_vector_type(4))) float f32x4;
typedef __attribute__((ext_vector_type(8))) u16 us8;

__device__ __forceinline__ float wredsum(float v) {
#pragma unroll
    for (int off = 32; off; off >>= 1) v += __shfl_xor(v, off);
    return v;
}

__device__ __forceinline__ u16 f2bf(float f) {
    u32 u = __float_as_uint(f);
    u32 r = (u + 0x7FFFu + ((u >> 16) & 1u)) >> 16;
    return (u16)r;
}
__device__ __forceinline__ float bf2f(u16 u) {
    return __uint_as_float((u32)u << 16);
}
// packed RNE f32->bf16 pair (1 VALU op)
__device__ __forceinline__ u32 cvtpk(float lo, float hi) {
    u32 r;
    asm("v_cvt_pk_bf16_f32 %0, %1, %2" : "=v"(r) : "v"(lo), "v"(hi));
    return r;
}

// direct global->LDS DMA, 16 B per lane; dest = lds_base + lane*16 (wave-uniform base)
__device__ __forceinline__ void gll16(const u16* g, u16* l) {
    __builtin_amdgcn_global_load_lds(
        (const __attribute__((address_space(1))) void*)g,
        (__attribute__((address_space(3))) void*)l,
        16, 0, 0);
}

// ---------------- Prep: W fp32 -> bf16 (same layout); x[b][k][m] -> xT[b][m][k] bf16 ----------------
__global__ __launch_bounds__(256) void prep_kernel(
        const float* __restrict__ x, const float* __restrict__ Wq,
        const float* __restrict__ Wk, const float* __restrict__ Wv,
        u16* __restrict__ Wbf, u16* __restrict__ xT) {
    const int bx = blockIdx.x;
    const int tid = threadIdx.x;
    if (bx < 1536) {                       // W convert: 3 x 512 blocks x 2048 elements
        const int w = bx >> 9;
        const int blk = bx & 511;
        const float* W = (w == 0) ? Wq : (w == 1) ? Wk : Wv;
        const size_t base = (size_t)blk * 2048 + (size_t)tid * 8;
        float4 f0 = *(const float4*)&W[base];
        float4 f1 = *(const float4*)&W[base + 4];
        us8 o;
        o[0] = f2bf(f0.x); o[1] = f2bf(f0.y); o[2] = f2bf(f0.z); o[3] = f2bf(f0.w);
        o[4] = f2bf(f1.x); o[5] = f2bf(f1.y); o[6] = f2bf(f1.z); o[7] = f2bf(f1.w);
        *(us8*)&Wbf[(size_t)w * 1048576 + base] = o;
    } else {                               // x transpose: 128 blocks (b, ktile)
        const int blk = bx - 1536;
        const int b = blk >> 4, kt = blk & 15;
        __shared__ float T[64][65];
        const int r16 = tid >> 4, c4 = (tid & 15) * 4;
#pragma unroll
        for (int s = 0; s < 4; s++) {
            int r = r16 + s * 16;
            *(float4*)&T[r][c4] = *(const float4*)&x[((size_t)b * L_SEQ + kt * 64 + r) * NM + c4];
        }
        __syncthreads();
        const int m = tid >> 2;
#pragma unroll
        for (int s = 0; s < 2; s++) {
            int c = (tid & 3) * 2 + s;
            int k0 = c * 8;
            us8 o;
#pragma unroll
            for (int j = 0; j < 8; j++) o[j] = f2bf(T[k0 + j][m]);
            *(us8*)&xT[((size_t)b * NM + m) * L_SEQ + kt * 64 + k0] = o;
        }
    }
}

// ---------------- Projection via MFMA, K-split x4, global_load_lds staging (round-16 form) --------
__global__ __launch_bounds__(256) void proj_mfma(
        const u16* __restrict__ Wbf, const u16* __restrict__ xT,
        u16* __restrict__ H, u16* __restrict__ VtG) {
    const int b  = blockIdx.x;   // 8 (fastest: consecutive blocks share the W tile in L2)
    const int it = blockIdx.y;   // 32 row tiles
    const int w  = blockIdx.z;   // 3
    const int tid = threadIdx.x;
    const int wv = tid >> 6, l = tid & 63;

    __shared__ __align__(16) u16 Ab[4][2048];   // per-wave [32 rows][64 k] swizzled
    __shared__ __align__(16) u16 Bb[4][4096];   // per-wave [64 m][64 k] swizzled; reused as fp32 partials

    const u16* As = Wbf + (size_t)w * 1048576 + (size_t)(it * 32) * L_SEQ;
    const u16* Bs = xT + (size_t)b * (NM * L_SEQ);

    const int soff = (l >> 3) * L_SEQ + (((l & 7) ^ (l >> 3)) * 8);

    f32x4 acc[2][4];
#pragma unroll
    for (int i = 0; i < 2; i++)
#pragma unroll
        for (int j = 0; j < 4; j++) acc[i][j] = (f32x4){0.f, 0.f, 0.f, 0.f};

#define ISSUE(kt) do { \
    _Pragma("unroll") for (int ti = 0; ti < 4; ti++) \
        gll16(&As[(size_t)ti * 8192 + soff + (kt) * 64], &Ab[wv][ti * 512]); \
    _Pragma("unroll") for (int ti = 0; ti < 8; ti++) \
        gll16(&Bs[(size_t)ti * 8192 + soff + (kt) * 64], &Bb[wv][ti * 512]); \
} while (0)

    const int frow = l & 15;
    const int fg = l >> 4;
    const int lx = l & 7;
    const int kt0 = wv * 4;

    ISSUE(kt0);
    asm volatile("s_waitcnt vmcnt(0)" ::: "memory");
    __builtin_amdgcn_sched_barrier(0);

    for (int ii = 0; ii < 4; ++ii) {
        short8 af[2][2], bf[2][4];
#pragma unroll
        for (int ks = 0; ks < 2; ++ks) {
            const int ch = ((ks * 4 + fg) ^ lx) * 8;
            af[ks][0] = *(const short8*)&Ab[wv][frow * 64 + ch];
            af[ks][1] = *(const short8*)&Ab[wv][(16 + frow) * 64 + ch];
#pragma unroll
            for (int cg = 0; cg < 4; ++cg)
                bf[ks][cg] = *(const short8*)&Bb[wv][(cg * 16 + frow) * 64 + ch];
        }
        asm volatile("s_waitcnt lgkmcnt(0)" ::: "memory");   // frags in VGPRs before DMA overwrite
        __builtin_amdgcn_sched_barrier(0);
        if (ii < 3) ISSUE(kt0 + ii + 1);                     // DMAs fly during MFMAs
#pragma unroll
        for (int ks = 0; ks < 2; ++ks)
#pragma unroll
            for (int cg = 0; cg < 4; ++cg) {
                acc[0][cg] = __builtin_amdgcn_mfma_f32_16x16x32_bf16(af[ks][0], bf[ks][cg], acc[0][cg], 0, 0, 0);
                acc[1][cg] = __builtin_amdgcn_mfma_f32_16x16x32_bf16(af[ks][1], bf[ks][cg], acc[1][cg], 0, 0, 0);
            }
        if (ii < 3) {
            asm volatile("s_waitcnt vmcnt(0)" ::: "memory"); // next tile landed before its ds_reads
            __builtin_amdgcn_sched_barrier(0);
        }
    }
#undef ISSUE

    // ---- reduce 4 K-partials through Bb (fp32 view), then parallel epilogue ----
    __syncthreads();
    float* Pp = (float*)&Bb[0][0];
#pragma unroll
    for (int rg = 0; rg < 2; ++rg)
#pragma unroll
        for (int cg = 0; cg < 4; ++cg)
#pragma unroll
            for (int r = 0; r < 4; ++r)
                Pp[wv * 2048 + (rg * 16 + fg * 4 + r) * 64 + cg * 16 + frow] = acc[rg][cg][r];
    __syncthreads();

    {
        const int row = wv * 8 + (l >> 3);
        const int c8  = (l & 7) * 8;
        f32x4 s0 = *(const f32x4*)&Pp[row * 64 + c8];
        f32x4 s1 = *(const f32x4*)&Pp[row * 64 + c8 + 4];
#pragma unroll
        for (int p = 1; p < 4; ++p) {
            f32x4 t0 = *(const f32x4*)&Pp[p * 2048 + row * 64 + c8];
            f32x4 t1 = *(const f32x4*)&Pp[p * 2048 + row * 64 + c8 + 4];
            s0 += t0; s1 += t1;
        }
        const int iq = it * 32 + row;
        const int c  = c8 >> 3;
        us8 o;
        o[0] = f2bf(s0[0]); o[1] = f2bf(s0[1]); o[2] = f2bf(s0[2]); o[3] = f2bf(s0[3]);
        o[4] = f2bf(s1[0]); o[5] = f2bf(s1[1]); o[6] = f2bf(s1[2]); o[7] = f2bf(s1[3]);
        u16* dst = H + (size_t)w * 524288 + (size_t)b * 65536;
        *(us8*)&dst[((size_t)c * L_SEQ + iq) * 8] = o;
        if (w == 2) {
#pragma unroll
            for (int j = 0; j < 8; ++j)
                VtG[((size_t)(b * 8 + c) * 8 + j) * L_SEQ + iq] = o[j];
        }
    }
}

// ---------------- MFMA attention (512 blocks, pair-balanced) + out2 (8 blocks), one launch --------
// Blocks 0..511: (s,c,b) decode; query tiles qlo=s, qhi=15-s sequentially per wave.
// Blocks 512..519: out2 for batch b = u-512. Both read only H/VtG; disjoint outputs.
// K staging via global_load_lds (dest = wave base + lane*16; kend 64-aligned -> wave-granular).
__global__ __launch_bounds__(256) void attn_mfma(
        const u16* __restrict__ H, const u16* __restrict__ VtG,
        const float* __restrict__ x, const float* __restrict__ pm,
        float* __restrict__ out) {
    const int u = blockIdx.x;    // 0..519
    const int tid = threadIdx.x;
    const int wv = tid >> 6, lane = tid & 63;

    __shared__ __align__(16) u16 Kl[8192];          // [1024 keys][8 d] bf16
    __shared__ __align__(16) u16 Vtl[8 * 1032];     // [8 d][1024+8 keys] bf16 (padded rows)

    if (u < 512) {
        const int s = u & 7, c = (u >> 3) & 7, b = u >> 6;
        const int qtil = lane & 15, g = lane >> 4;

        const size_t hoff = (size_t)(b * 8 + c) * 8192;
        const u16* HQ = H + hoff;
        const u16* HK = H + 524288 + hoff;
        const int qlo = s, qhi = 15 - s;
        const int kend = (qhi + 1) * 64;     // superset: covers both tiles' needs

        // stage K rows via direct DMA (16 B/lane, linear dest)
        for (int k = tid; k < kend; k += 256)
            gll16(&HK[(size_t)k * 8], &Kl[k * 8]);
        // stage V^T rows (padded stride -> reg-staged)
        {
            const int vd = tid >> 5;                    // 0..7
            const u16* src = VtG + ((size_t)(b * 8 + c) * 8 + vd) * L_SEQ;
            for (int k8 = (tid & 31) * 8; k8 < kend; k8 += 256)
                *(us8*)&Vtl[vd * 1032 + k8] = *(const us8*)&src[k8];
        }

        // Q fragments for both tiles (scaled bf16; g=0 lanes carry data, others zero-pad depth)
        short8 qfLo = {0, 0, 0, 0, 0, 0, 0, 0};
        short8 qfHi = {0, 0, 0, 0, 0, 0, 0, 0};
        {
            const float sc = RS8 * LOG2E;
            us8 qvLo = *(const us8*)&HQ[(size_t)(qlo * 64 + wv * 16 + qtil) * 8];
            us8 qvHi = *(const us8*)&HQ[(size_t)(qhi * 64 + wv * 16 + qtil) * 8];
            if (g == 0) {
#pragma unroll
                for (int j = 0; j < 8; j++) {
                    qfLo[j] = (short)f2bf(bf2f(qvLo[j]) * sc);
                    qfHi[j] = (short)f2bf(bf2f(qvHi[j]) * sc);
                }
            }
        }

        __syncthreads();    // drains vmcnt (DMA) + lgkm before any LDS read

        const f32x4 czero = {0.f, 0.f, 0.f, 0.f};
        const short8 z8 = {0, 0, 0, 0, 0, 0, 0, 0};

#define ACHUNK2(QF, ch, PRED) do { \
    const int kb_ = (ch) * 32; \
    short8 kfA_ = z8, kfB_ = z8; \
    if (g == 0) { \
        kfA_ = *(const short8*)&Kl[(kb_ + qtil) * 8]; \
        kfB_ = *(const short8*)&Kl[(kb_ + 16 + qtil) * 8]; \
    } \
    f32x4 dA_ = __builtin_amdgcn_mfma_f32_16x16x32_bf16(kfA_, QF, czero, 0, 0, 0); \
    f32x4 dB_ = __builtin_amdgcn_mfma_f32_16x16x32_bf16(kfB_, QF, czero, 0, 0, 0); \
    float pA_[4], pB_[4]; \
    const int keyA_ = kb_ + 4 * g; \
    _Pragma("unroll") for (int r_ = 0; r_ < 4; r_++) { \
        pA_[r_] = exp2f(dA_[r_]); \
        pB_[r_] = exp2f(dB_[r_]); \
        if (PRED) { \
            pA_[r_] = (keyA_ + r_ <= q_) ? pA_[r_] : 0.f; \
            pB_[r_] = (keyA_ + 16 + r_ <= q_) ? pB_[r_] : 0.f; \
        } \
        lsum_ += pA_[r_] + pB_[r_]; \
    } \
    const u32 A01_ = cvtpk(pA_[0], pA_[1]), A23_ = cvtpk(pA_[2], pA_[3]); \
    const u32 B01_ = cvtpk(pB_[0], pB_[1]), B23_ = cvtpk(pB_[2], pB_[3]); \
    const int src_ = qtil + ((g & 1) << 5); \
    const u32 a0_ = (u32)__shfl((int)A01_, src_, 64); \
    const u32 a1_ = (u32)__shfl((int)A23_, src_, 64); \
    const u32 a2_ = (u32)__shfl((int)A01_, src_ + 16, 64); \
    const u32 a3_ = (u32)__shfl((int)A23_, src_ + 16, 64); \
    const u32 b0_ = (u32)__shfl((int)B01_, src_, 64); \
    const u32 b1_ = (u32)__shfl((int)B23_, src_, 64); \
    const u32 b2_ = (u32)__shfl((int)B01_, src_ + 16, 64); \
    const u32 b3_ = (u32)__shfl((int)B23_, src_ + 16, 64); \
    union { u32 u[4]; short8 s; } pu_; \
    pu_.u[0] = (g < 2) ? a0_ : b0_; \
    pu_.u[1] = (g < 2) ? a1_ : b1_; \
    pu_.u[2] = (g < 2) ? a2_ : b2_; \
    pu_.u[3] = (g < 2) ? a3_ : b3_; \
    short8 vf_ = z8; \
    if (qtil < 8) vf_ = *(const short8*)&Vtl[qtil * 1032 + kb_ + 8 * g]; \
    oacc_ = __builtin_amdgcn_mfma_f32_16x16x32_bf16(vf_, pu_.s, oacc_, 0, 0, 0); \
} while (0)

#define RUNPASS(QF, TILE) do { \
    const int base_ = (TILE) * 64 + wv * 16; \
    const int q_ = base_ + qtil; \
    f32x4 oacc_ = czero; \
    float lsum_ = 0.f; \
    const int nfull_ = (base_ + 1) >> 5; \
    const int nch_ = (base_ + 47) >> 5; \
    for (int ch_ = 0; ch_ < nfull_; ++ch_) ACHUNK2(QF, ch_, false); \
    for (int ch_ = nfull_; ch_ < nch_; ++ch_) ACHUNK2(QF, ch_, true); \
    lsum_ += __shfl_xor(lsum_, 16); \
    lsum_ += __shfl_xor(lsum_, 32); \
    if (g < 2) { \
        const float qm_ = pm[b * L_SEQ + q_]; \
        const float r8_ = qm_ / lsum_; \
        const size_t off_ = (size_t)b * LM + (size_t)q_ * NM + c * 8 + g * 4; \
        float4 xv_ = *(const float4*)&x[off_]; \
        float4 o_ = make_float4(fmaf(oacc_[0], r8_, xv_.x), fmaf(oacc_[1], r8_, xv_.y), \
                                fmaf(oacc_[2], r8_, xv_.z), fmaf(oacc_[3], r8_, xv_.w)); \
        *(float4*)&out[off_] = o_; \
    } \
} while (0)

        RUNPASS(qfLo, qlo);
        RUNPASS(qfHi, qhi);
#undef RUNPASS
#undef ACHUNK2
    } else {
        // ---------------- out2: attention[b][k] = qm(b,1023)/8 * sum_c softmax_row_c[k] ----------
        const int b = u - 512;
        float* red = (float*)Kl;
        const float qm = pm[b * L_SEQ + 1023];
        const float sc = RS8 * LOG2E;
        float acc[4] = {0.f, 0.f, 0.f, 0.f};
        float* out2 = out + BLM;
        for (int cc = 0; cc < 8; cc++) {
            const size_t hoff = (size_t)(b * 8 + cc) * 8192;
            us8 qv = *(const us8*)&H[hoff + (size_t)1023 * 8];
            const float q0 = bf2f(qv[0]) * sc, q1 = bf2f(qv[1]) * sc;
            const float q2 = bf2f(qv[2]) * sc, q3 = bf2f(qv[3]) * sc;
            const float q4 = bf2f(qv[4]) * sc, q5 = bf2f(qv[5]) * sc;
            const float q6 = bf2f(qv[6]) * sc, q7 = bf2f(qv[7]) * sc;
            const u16* Kg = H + 524288 + hoff;
            float p[4];
            float ts = 0.f;
#pragma unroll
            for (int i = 0; i < 4; i++) {
                int k = tid + 256 * i;
                us8 kv = *(const us8*)&Kg[(size_t)k * 8];
                float sa = fmaf(q0, bf2f(kv[0]), fmaf(q1, bf2f(kv[1]), fmaf(q2, bf2f(kv[2]), q3 * bf2f(kv[3]))));
                float sb = fmaf(q4, bf2f(kv[4]), fmaf(q5, bf2f(kv[5]), fmaf(q6, bf2f(kv[6]), q7 * bf2f(kv[7]))));
                p[i] = exp2f(sa + sb);
                ts += p[i];
            }
            ts = wredsum(ts);
            if (lane == 0) red[wv] = ts;
            __syncthreads();
            const float inv = 0.125f / (red[0] + red[1] + red[2] + red[3]);
            __syncthreads();
#pragma unroll
            for (int i = 0; i < 4; i++) acc[i] = fmaf(p[i], inv, acc[i]);
        }
#pragma unroll
        for (int i = 0; i < 4; i++) out2[b * L_SEQ + tid + 256 * i] = acc[i] * qm;
    }
}

extern "C" void kernel_launch(void* const* d_in, const int* in_sizes, int n_in,
                              void* d_out, int out_size, void* d_ws, size_t ws_size,
                              hipStream_t stream) {
    const float* x  = (const float*)d_in[0];
    const float* pm = (const float*)d_in[1];
    const float* Wq = (const float*)d_in[2];
    const float* Wk = (const float*)d_in[3];
    const float* Wv = (const float*)d_in[4];

    u16* H    = (u16*)d_ws;                              // 3 MB bf16 head-major Q,K,V
    u16* Wbf  = (u16*)((char*)d_ws + 3145728);           // 6 MB bf16 W[3][1024][1024]
    u16* xT   = (u16*)((char*)d_ws + 9437184);           // 1 MB bf16 xT[8][64][1024]
    u16* VtG  = (u16*)((char*)d_ws + 10485760);          // 1 MB bf16 Vt[64 heads][8][1024]
    float* out = (float*)d_out;                          // [8,1024,64] then [8,1024]

    hipLaunchKernelGGL(prep_kernel, dim3(1664), dim3(256), 0, stream, x, Wq, Wk, Wv, Wbf, xT);
    hipLaunchKernelGGL(proj_mfma, dim3(8, 32, 3), dim3(256), 0, stream, Wbf, xT, H, VtG);
    hipLaunchKernelGGL(attn_mfma, dim3(520), dim3(256), 0, stream, H, VtG, x, pm, out);
}